// Round 2
// baseline (508.207 us; speedup 1.0000x reference)
//
#include <hip/hip_runtime.h>

#define ROW 120
#define CHUNK 16   // rows per block iteration

// ---------------------------------------------------------------------------
// Pass 1 (fused): for each row —
//   * LayerNorm cols 0..31  -> out
//   * vec cols 32..79:  write feats / max(norm,1e-6)  -> out, accumulate norm
//   * ten cols 80..119: write feats / max(norm,1e-6)  -> out, accumulate norm
// Channel norm sums accumulated into sums[0..15] (vec) / sums[16..23] (ten).
// Single read of x, single write of out, fully float4-coalesced via LDS.
// ---------------------------------------------------------------------------
__global__ __launch_bounds__(256) void pass1(const float* __restrict__ x,
                                             const float* __restrict__ w,
                                             const float* __restrict__ b,
                                             float* __restrict__ out,
                                             float* __restrict__ sums,
                                             int N) {
    __shared__ float lds[CHUNK * ROW];
    __shared__ float red[256];
    const int tid = threadIdx.x;
    const int l   = tid & 15;

    const float w0 = w[2 * l], w1 = w[2 * l + 1];
    const float b0 = b[2 * l], b1 = b[2 * l + 1];

    float accV = 0.f;   // vec channel = tid & 15
    float accT = 0.f;   // ten channel = tid & 7  (tid < 128 only)

    const int nChunks = N / CHUNK;   // N = 524288, divisible by 16
    for (int ch = blockIdx.x; ch < nChunks; ch += gridDim.x) {
        const int row0 = ch * CHUNK;
        // stage 16 full rows: global layout == LDS layout, contiguous float4
        #pragma unroll
        for (int i = tid; i < CHUNK * 30; i += 256)
            *(float4*)(lds + i * 4) = *(const float4*)(x + (size_t)row0 * ROW + i * 4);
        __syncthreads();

        // --- LayerNorm: 16 lanes per row, 2 scalars per lane ---
        {
            const int r = tid >> 4;
            float* base = lds + r * ROW;
            const float x0 = base[2 * l], x1 = base[2 * l + 1];
            float s  = x0 + x1;
            float sq = x0 * x0 + x1 * x1;
            #pragma unroll
            for (int m = 1; m < 16; m <<= 1) {
                s  += __shfl_xor(s, m);
                sq += __shfl_xor(sq, m);
            }
            const float mu   = s * (1.f / 32.f);
            const float var  = sq * (1.f / 32.f) - mu * mu;
            const float rstd = rsqrtf(var + 1e-5f);
            base[2 * l]     = (x0 - mu) * rstd * w0 + b0;
            base[2 * l + 1] = (x1 - mu) * rstd * w1 + b1;
        }
        // --- vec: one thread per (row, vec channel); write feats/n ---
        {
            const int r = tid >> 4, v = tid & 15;
            float* p = lds + r * ROW + 32 + 3 * v;
            const float n  = fmaxf(sqrtf(p[0]*p[0] + p[1]*p[1] + p[2]*p[2]), 1e-6f);
            accV += n;
            const float sc = 1.0f / n;
            p[0] *= sc; p[1] *= sc; p[2] *= sc;
        }
        // --- ten: one thread per (row, ten channel); write feats/n ---
        if (tid < 128) {
            const int r = tid >> 3, c = tid & 7;
            float* p = lds + r * ROW + 80 + 5 * c;
            const float n  = fmaxf(sqrtf(p[0]*p[0] + p[1]*p[1] + p[2]*p[2]
                                       + p[3]*p[3] + p[4]*p[4]), 1e-6f);
            accT += n;
            const float sc = 1.0f / n;
            #pragma unroll
            for (int j = 0; j < 5; ++j) p[j] *= sc;
        }
        __syncthreads();

        // coalesced float4 store of the full 16 rows
        #pragma unroll
        for (int i = tid; i < CHUNK * 30; i += 256)
            *(float4*)(out + (size_t)row0 * ROW + i * 4) = *(const float4*)(lds + i * 4);
        __syncthreads();
    }

    // block-level channel reduction, one atomicAdd per channel per block
    red[tid] = accV;
    __syncthreads();
    if (tid < 16) {
        float s = 0.f;
        #pragma unroll
        for (int k = 0; k < 16; ++k) s += red[tid + 16 * k];
        atomicAdd(&sums[tid], s);
    }
    __syncthreads();
    red[tid] = (tid < 128) ? accT : 0.f;
    __syncthreads();
    if (tid < 8) {
        float s = 0.f;
        #pragma unroll
        for (int k = 0; k < 16; ++k) s += red[tid + 8 * k];
        atomicAdd(&sums[16 + tid], s);
    }
}

// ---------------------------------------------------------------------------
// Pass 2: out[row, col] *= colscale[col] for col in 32..119, where
// colscale[col] = mean_norm[channel(col)].  Pure per-column constant scale:
// grid-stride float4 RMW over the 22 float4s per row of the vec/ten region.
// ---------------------------------------------------------------------------
__global__ __launch_bounds__(256) void pass2(float* __restrict__ out,
                                             const float* __restrict__ sums,
                                             int N, float invN) {
    __shared__ float sctab[88];
    const int tid = threadIdx.x;
    if (tid < 88) {
        const int col = 32 + tid;
        sctab[tid] = (col < 80) ? sums[(col - 32) / 3] * invN
                                : sums[16 + (col - 80) / 5] * invN;
    }
    __syncthreads();

    const int total  = N * 22;                       // float4 elements to touch
    const int stride = gridDim.x * 256;
    for (int e = blockIdx.x * 256 + tid; e < total; e += stride) {
        const int row = e / 22, q = e - row * 22;
        float4* p = (float4*)(out + (size_t)row * ROW + 32 + q * 4);
        float4 v = *p;
        v.x *= sctab[q * 4 + 0];
        v.y *= sctab[q * 4 + 1];
        v.z *= sctab[q * 4 + 2];
        v.w *= sctab[q * 4 + 3];
        *p = v;
    }
}

extern "C" void kernel_launch(void* const* d_in, const int* in_sizes, int n_in,
                              void* d_out, int out_size, void* d_ws, size_t ws_size,
                              hipStream_t stream) {
    const float* x = (const float*)d_in[0];
    const float* w = (const float*)d_in[1];
    const float* b = (const float*)d_in[2];
    float* out  = (float*)d_out;
    float* sums = (float*)d_ws;
    const int N = in_sizes[0] / ROW;

    hipMemsetAsync(d_ws, 0, 24 * sizeof(float), stream);  // ws re-poisoned each call
    pass1<<<2048, 256, 0, stream>>>(x, w, b, out, sums, N);
    pass2<<<2048, 256, 0, stream>>>(out, sums, N, 1.0f / (float)N);
}